// Round 1
// baseline (33064.539 us; speedup 1.0000x reference)
//
#include <hip/hip_runtime.h>
#include <hip/hip_bf16.h>

#define LSEQ 32768
#define L2E 1.4426950408889634f

// ---------------- P1: xm[v][j] = b_im[j] + sum_e w_im[j,e]*emb[v,e] ----------------
__global__ void precompute_xm(const float* __restrict__ emb,
                              const float* __restrict__ w_im,
                              const float* __restrict__ b_im,
                              float* __restrict__ xmws) {
    int tid = (int)threadIdx.x;  // 384 threads: v = tid>>6, j = tid&63
    int v = tid >> 6, j = tid & 63;
    float acc = b_im[j];
    for (int e = 0; e < 32; ++e) acc = fmaf(w_im[j * 32 + e], emb[v * 32 + e], acc);
    xmws[v * 64 + j] = acc;
}

// ---------------- P2: fused matrix M_v = s_r * W_hh . diag(xm_v) . W_hm  ----------
//                     and bias_v[r] = s_r * (W_ih emb_v + b_ih + b_hh + W_hh (xm_v .* b_hm))
// s_r = -log2(e) for sigmoid rows (i,f,o), -2*log2(e) for tanh rows (g: 128..191)
__global__ void precompute_M(const float* __restrict__ emb,
                             const float* __restrict__ w_hm,
                             const float* __restrict__ b_hm,
                             const float* __restrict__ W_ih,
                             const float* __restrict__ b_ih,
                             const float* __restrict__ W_hh,
                             const float* __restrict__ b_hh,
                             const float* __restrict__ xmws,
                             float* __restrict__ Mws,
                             float* __restrict__ biasws) {
    int n = blockIdx.x * 256 + (int)threadIdx.x;  // 0..98303
    int v = n >> 14;
    int r = (n >> 6) & 255;
    int k = n & 63;
    float s = (r >= 128 && r < 192) ? (-2.0f * L2E) : (-L2E);
    float acc = 0.0f;
    for (int jj = 0; jj < 64; ++jj)
        acc = fmaf(W_hh[r * 64 + jj] * xmws[v * 64 + jj], w_hm[jj * 64 + k], acc);
    // layout so the main kernel's lane tid loads float4s coalesced:
    // M[v][r][half*32 + q*4 + c] -> Mws[4*((v*8+q)*512 + r*2+half) + c]
    int half = k >> 5, q = (k & 31) >> 2, c4 = k & 3;
    Mws[4 * ((v * 8 + q) * 512 + r * 2 + half) + c4] = s * acc;
    if (k == 0) {
        float b = b_ih[r] + b_hh[r];
        for (int e = 0; e < 32; ++e) b = fmaf(W_ih[r * 32 + e], emb[v * 32 + e], b);
        for (int jj = 0; jj < 64; ++jj)
            b = fmaf(W_hh[r * 64 + jj] * xmws[v * 64 + jj], b_hm[jj], b);
        biasws[v * 256 + r] = s * b;
    }
}

// ---------------- main serial kernel: 1 workgroup, 8 waves ----------------
// lane owns gate row r = tid>>1, k-half = tid&1. M in registers (192 VGPRs).
// Per step: 6-way uniform branch -> 32 ds_bpermute + 32 fma; shfl_xor pair-reduce;
// exp2/rcp activation; one LDS exchange (double-buffered) + one barrier;
// redundant per-wave c/h update keeps h wave-local for bpermute.
__global__ __launch_bounds__(512, 2) void mlstm_main(
    const int* __restrict__ seq,
    const float* __restrict__ Mws,
    const float* __restrict__ biasws,
    const float* __restrict__ W_out,
    const float* __restrict__ b_out,
    float* __restrict__ out)
{
    const int tid = (int)threadIdx.x;
    const int r = tid >> 1;
    const int half = tid & 1;
    const int j = tid & 63;

    __shared__ float gbuf[2][256];
    __shared__ float cbuf[64];

    float M[192];
    const float4* M4 = (const float4*)Mws;
    #pragma unroll
    for (int v = 0; v < 6; ++v) {
        #pragma unroll
        for (int q = 0; q < 8; ++q) {
            float4 f = M4[(v * 8 + q) * 512 + tid];
            M[v * 32 + q * 4 + 0] = f.x;
            M[v * 32 + q * 4 + 1] = f.y;
            M[v * 32 + q * 4 + 2] = f.z;
            M[v * 32 + q * 4 + 3] = f.w;
        }
    }
    float bias[6];
    #pragma unroll
    for (int v = 0; v < 6; ++v) bias[v] = biasws[v * 256 + r];

    const bool is_g = ((tid >> 7) == 2);      // rows 128..191 = g (tanh)
    const float act_s = is_g ? 2.0f : 1.0f;   // act = act_s * sig + act_b
    const float act_b = is_g ? -1.0f : 0.0f;
    const int bpb = half * 128;               // bpermute byte base: lane = half*32 + q

    float c = 0.0f, h = 0.0f;
    // scalar sequence prefetch pipeline, distance 6
    int s0 = seq[0], s1 = seq[1], s2 = seq[2], s3 = seq[3], s4 = seq[4], s5 = seq[5];

    for (int t = 0; t < LSEQ; ++t) {
        const int v = s0;
        s0 = s1; s1 = s2; s2 = s3; s3 = s4; s4 = s5;
        int tn = t + 6; tn = tn > (LSEQ - 1) ? (LSEQ - 1) : tn;
        s5 = seq[tn];

        const int hb = __float_as_int(h);
        float acc, bv;
        #define ARM(V) { float a0 = 0.0f, a1 = 0.0f; \
          _Pragma("unroll") \
          for (int q = 0; q < 32; q += 2) { \
            float x0 = __int_as_float(__builtin_amdgcn_ds_bpermute(bpb + 4 * q, hb)); \
            float x1 = __int_as_float(__builtin_amdgcn_ds_bpermute(bpb + 4 * q + 4, hb)); \
            a0 = fmaf(M[(V) * 32 + q],     x0, a0); \
            a1 = fmaf(M[(V) * 32 + q + 1], x1, a1); \
          } \
          acc = a0 + a1; bv = bias[(V)]; }
        switch (v) {
          case 0: ARM(0); break;
          case 1: ARM(1); break;
          case 2: ARM(2); break;
          case 3: ARM(3); break;
          case 4: ARM(4); break;
          default: ARM(5); break;
        }
        #undef ARM

        // full (prescaled) gate = own half + partner half + bias
        float gate = acc + __shfl_xor(acc, 1, 64) + bv;
        // sigmoid(raw) = 1/(1+2^gate); tanh(raw) = 2/(1+2^gate) - 1 (prescale folded in M)
        float a = __builtin_amdgcn_rcpf(1.0f + __builtin_amdgcn_exp2f(gate));
        float ga = fmaf(act_s, a, act_b);

        if (half == 0) gbuf[t & 1][r] = ga;
        __syncthreads();
        const float* gg = gbuf[t & 1];
        float iv = gg[j], fv = gg[64 + j], gv = gg[128 + j], ov = gg[192 + j];
        c = fmaf(fv, c, iv * gv);
        float tc = fmaf(2.0f,
                        __builtin_amdgcn_rcpf(1.0f + __builtin_amdgcn_exp2f(c * (-2.0f * L2E))),
                        -1.0f);
        h = ov * tc;  // every lane holds h[tid&63] -> h stays wave-local for bpermute
    }

    if (tid < 64) cbuf[tid] = c;
    __syncthreads();
    if (tid < 8) {
        float sacc = b_out[tid];
        for (int k2 = 0; k2 < 64; ++k2)
            sacc = fmaf(W_out[tid * 64 + k2], cbuf[k2], sacc);
        out[tid] = sacc;
    }
}

extern "C" void kernel_launch(void* const* d_in, const int* in_sizes, int n_in,
                              void* d_out, int out_size, void* d_ws, size_t ws_size,
                              hipStream_t stream) {
    const int*   seq   = (const int*)d_in[0];
    const float* emb   = (const float*)d_in[1];
    const float* w_im  = (const float*)d_in[2];
    const float* b_im  = (const float*)d_in[3];
    const float* w_hm  = (const float*)d_in[4];
    const float* b_hm  = (const float*)d_in[5];
    const float* W_ih  = (const float*)d_in[6];
    const float* b_ih  = (const float*)d_in[7];
    const float* W_hh  = (const float*)d_in[8];
    const float* b_hh  = (const float*)d_in[9];
    const float* W_out = (const float*)d_in[10];
    const float* b_out = (const float*)d_in[11];
    float* out = (float*)d_out;

    float* ws     = (float*)d_ws;
    float* xmws   = ws;          // 384 floats
    float* biasws = ws + 384;    // 1536 floats
    float* Mws    = ws + 2048;   // 98304 floats (16B-aligned offset)

    precompute_xm<<<1, 384, 0, stream>>>(emb, w_im, b_im, xmws);
    precompute_M<<<384, 256, 0, stream>>>(emb, w_hm, b_hm, W_ih, b_ih,
                                          W_hh, b_hh, xmws, Mws, biasws);
    mlstm_main<<<1, 512, 0, stream>>>(seq, Mws, biasws, W_out, b_out, out);
}

// Round 2
// 21995.813 us; speedup vs baseline: 1.5032x; 1.5032x over previous
//
#include <hip/hip_runtime.h>
#include <hip/hip_bf16.h>

#define LSEQ 32768
#define L2E 1.4426950408889634f

// DPP controls
#define DPP_XOR1 0xB1   // quad_perm [1,0,3,2]
#define DPP_XOR2 0x4E   // quad_perm [2,3,0,1]
#define DPP_XOR7 0x141  // row_half_mirror (lane ^ 7 within each 8)

__device__ __forceinline__ float dppf(float x, const int ctrl_b1, const int ctrl_4e, const int ctrl_141, int which) {
    // not used; see DPPF macro
    return x;
}
#define DPPF(x, ctrl) __int_as_float(__builtin_amdgcn_update_dpp(0, __float_as_int(x), (ctrl), 0xF, 0xF, true))

// ---------------- P1: xm[v][j] = b_im[j] + sum_e w_im[j,e]*emb[v,e] ----------------
__global__ void precompute_xm(const float* __restrict__ emb,
                              const float* __restrict__ w_im,
                              const float* __restrict__ b_im,
                              float* __restrict__ xmws) {
    int tid = (int)threadIdx.x;  // 384 threads: v = tid>>6, j = tid&63
    int v = tid >> 6, j = tid & 63;
    float acc = b_im[j];
    for (int e = 0; e < 32; ++e) acc = fmaf(w_im[j * 32 + e], emb[v * 32 + e], acc);
    xmws[v * 64 + j] = acc;
}

// ---------------- P2: M_v = s_r * W_hh . diag(xm_v) . W_hm, bias folded+prescaled --
// Scatter into the main kernel's per-lane layout:
// lane tid = w*64 + jj*8 + gt*2 + hf   (w=ch>>3, jj=ch&7, gt=r>>6, ch=r&63, hf=k>>5)
// Mws[4*((v*8+q)*512 + tid) + c] = s_r * M_v[r][hf*32 + 4q + c]
__global__ void precompute_M(const float* __restrict__ emb,
                             const float* __restrict__ w_hm,
                             const float* __restrict__ b_hm,
                             const float* __restrict__ W_ih,
                             const float* __restrict__ b_ih,
                             const float* __restrict__ W_hh,
                             const float* __restrict__ b_hh,
                             const float* __restrict__ xmws,
                             float* __restrict__ Mws,
                             float* __restrict__ biasws) {
    int n = blockIdx.x * 256 + (int)threadIdx.x;  // 0..98303
    int v = n >> 14;
    int r = (n >> 6) & 255;
    int k = n & 63;
    int gt = r >> 6;
    float s = (gt == 2) ? (-2.0f * L2E) : (-L2E);
    float acc = 0.0f;
    for (int jj = 0; jj < 64; ++jj)
        acc = fmaf(W_hh[r * 64 + jj] * xmws[v * 64 + jj], w_hm[jj * 64 + k], acc);
    int ch = r & 63, w = ch >> 3, jg = ch & 7;
    int hf = k >> 5, q = (k >> 2) & 7, c4 = k & 3;
    int tid = w * 64 + jg * 8 + gt * 2 + hf;
    Mws[4 * ((v * 8 + q) * 512 + tid) + c4] = s * acc;
    if ((k & 31) == 0) {  // once per (v, r, hf): bias
        float b = b_ih[r] + b_hh[r];
        for (int e = 0; e < 32; ++e) b = fmaf(W_ih[r * 32 + e], emb[v * 32 + e], b);
        for (int jj = 0; jj < 64; ++jj)
            b = fmaf(W_hh[r * 64 + jj] * xmws[v * 64 + jj], b_hm[jj], b);
        biasws[v * 512 + tid] = s * b;
    }
}

// ---------------- main serial kernel: 1 workgroup, 8 waves, channel-grouped -------
// wave w owns channels 8w..8w+7. lane l = jj*8 + gt*2 + hf.
// Per step: 8 broadcast ds_read_b128 (h) -> 32 FMA -> DPP xor1 half-combine ->
// exp2/rcp activation -> 3 DPP gate-butterfly + 8 cndmask -> c/h update (redundant
// per 8-lane group) -> 1 ds_write (h) -> barrier. One LDS round trip per step.
__global__ __launch_bounds__(512) __attribute__((amdgpu_waves_per_eu(2, 2)))
void mlstm_main(
    const int* __restrict__ seq,
    const float* __restrict__ Mws,
    const float* __restrict__ biasws,
    const float* __restrict__ W_out,
    const float* __restrict__ b_out,
    float* __restrict__ out)
{
    const int tid = (int)threadIdx.x;
    const int w = tid >> 6;
    const int l = tid & 63;
    const int hf = l & 1;
    const int p = (l >> 1) & 3;       // gate index: 0=i 1=f 2=g 3=o
    const int ch = w * 8 + (l >> 3);  // this lane's channel
    const bool b0 = (p & 1) != 0;
    const bool b1 = (p & 2) != 0;
    const bool is_g = (p == 2);
    const float act_s = is_g ? 2.0f : 1.0f;
    const float act_b = is_g ? -1.0f : 0.0f;

    __shared__ float hbuf[2][64];
    __shared__ float cvec[64];

    // ---- load M (192 floats) into registers with literal indices ----
    float M[192];
    const float4* M4 = (const float4*)Mws;
#define LDQ(V, Q) { float4 f_ = M4[((V) * 8 + (Q)) * 512 + tid]; \
    M[(V)*32+(Q)*4+0] = f_.x; M[(V)*32+(Q)*4+1] = f_.y; \
    M[(V)*32+(Q)*4+2] = f_.z; M[(V)*32+(Q)*4+3] = f_.w; }
#define LDV(V) LDQ(V,0) LDQ(V,1) LDQ(V,2) LDQ(V,3) LDQ(V,4) LDQ(V,5) LDQ(V,6) LDQ(V,7)
    LDV(0) LDV(1) LDV(2) LDV(3) LDV(4) LDV(5)
#undef LDV
#undef LDQ
    float bias[6];
#pragma unroll
    for (int v = 0; v < 6; ++v) bias[v] = biasws[v * 512 + tid];

    if (tid < 64) hbuf[1][tid] = 0.0f;
    __syncthreads();

    float c = 0.0f;
    int s0 = seq[0], s1 = seq[1], s2 = seq[2], s3 = seq[3], s4 = seq[4], s5 = seq[5];

    for (int t = 0; t < LSEQ; ++t) {
        const int v = s0;
        s0 = s1; s1 = s2; s2 = s3; s3 = s4; s4 = s5;
        int tn = t + 6; tn = tn > (LSEQ - 1) ? (LSEQ - 1) : tn;
        s5 = seq[tn];

        const int rb = (t & 1) ^ 1;   // read h_{t-1}
        const int wb = t & 1;         // write h_t

        // ---- broadcast-read h half (32 floats, 8x ds_read_b128, conflict-free) ----
        const float4* hb4 = (const float4*)(&hbuf[rb][0]);
        const int hq = hf * 8;
        float4 H0 = hb4[hq + 0], H1 = hb4[hq + 1], H2 = hb4[hq + 2], H3 = hb4[hq + 3];
        float4 H4 = hb4[hq + 4], H5 = hb4[hq + 5], H6 = hb4[hq + 6], H7 = hb4[hq + 7];

        float a0 = 0.0f, a1 = 0.0f, a2 = 0.0f, a3 = 0.0f;
#define MQ(V, Q, HV) \
        a0 = fmaf(M[(V)*32+(Q)*4+0], HV.x, a0); \
        a1 = fmaf(M[(V)*32+(Q)*4+1], HV.y, a1); \
        a2 = fmaf(M[(V)*32+(Q)*4+2], HV.z, a2); \
        a3 = fmaf(M[(V)*32+(Q)*4+3], HV.w, a3);
#define ARM(V) { MQ(V,0,H0) MQ(V,1,H1) MQ(V,2,H2) MQ(V,3,H3) \
                 MQ(V,4,H4) MQ(V,5,H5) MQ(V,6,H6) MQ(V,7,H7) bv = bias[V]; }
        float bv;
        switch (v) {
            case 0: ARM(0); break;
            case 1: ARM(1); break;
            case 2: ARM(2); break;
            case 3: ARM(3); break;
            case 4: ARM(4); break;
            default: ARM(5); break;
        }
#undef ARM
#undef MQ
        float acc = (a0 + a1) + (a2 + a3);
        // half-combine via DPP xor1 (both halves end with the full dot)
        float full = acc + DPPF(acc, DPP_XOR1) + bv;

        // activation (prescale folded into M/bias): sig = 1/(1+2^x); tanh via 2*sig-1
        float sg = __builtin_amdgcn_rcpf(1.0f + __builtin_amdgcn_exp2f(full));
        float V_ = fmaf(act_s, sg, act_b);   // this lane's gate value

        // gate butterfly: V_->p, W_->p^1, X_->p^3, Y_->p^2
        float W_ = DPPF(V_, DPP_XOR2);
        float X_ = DPPF(V_, DPP_XOR7);
        float Y_ = DPPF(W_, DPP_XOR7);

        // select i,f,g,o (8 cndmask)
        float t0 = b0 ? W_ : V_;
        float t1 = b0 ? X_ : Y_;
        float u0 = b0 ? V_ : W_;
        float u1 = b0 ? Y_ : X_;
        float gi = b1 ? t1 : t0;
        float gf = b1 ? u1 : u0;
        float gg = b1 ? t0 : t1;
        float go = b1 ? u0 : u1;

        c = fmaf(gf, c, gi * gg);
        float tc = fmaf(2.0f,
                        __builtin_amdgcn_rcpf(1.0f + __builtin_amdgcn_exp2f(c * (-2.0f * L2E))),
                        -1.0f);
        float h = go * tc;

        if ((l & 7) == 0) hbuf[wb][ch] = h;
        __syncthreads();
    }

    if ((l & 7) == 0) cvec[ch] = c;
    __syncthreads();
    if (tid < 8) {
        float sacc = b_out[tid];
        for (int k2 = 0; k2 < 64; ++k2)
            sacc = fmaf(W_out[tid * 64 + k2], cvec[k2], sacc);
        out[tid] = sacc;
    }
}

extern "C" void kernel_launch(void* const* d_in, const int* in_sizes, int n_in,
                              void* d_out, int out_size, void* d_ws, size_t ws_size,
                              hipStream_t stream) {
    const int*   seq   = (const int*)d_in[0];
    const float* emb   = (const float*)d_in[1];
    const float* w_im  = (const float*)d_in[2];
    const float* b_im  = (const float*)d_in[3];
    const float* w_hm  = (const float*)d_in[4];
    const float* b_hm  = (const float*)d_in[5];
    const float* W_ih  = (const float*)d_in[6];
    const float* b_ih  = (const float*)d_in[7];
    const float* W_hh  = (const float*)d_in[8];
    const float* b_hh  = (const float*)d_in[9];
    const float* W_out = (const float*)d_in[10];
    const float* b_out = (const float*)d_in[11];
    float* out = (float*)d_out;

    float* ws     = (float*)d_ws;
    float* xmws   = ws;           // 384 floats
    float* biasws = ws + 384;     // 3072 floats
    float* Mws    = ws + 3456;    // 98304 floats (3456*4 bytes, 16B-aligned)

    precompute_xm<<<1, 384, 0, stream>>>(emb, w_im, b_im, xmws);
    precompute_M<<<384, 256, 0, stream>>>(emb, w_hm, b_hm, W_ih, b_ih,
                                          W_hh, b_hh, xmws, Mws, biasws);
    mlstm_main<<<1, 512, 0, stream>>>(seq, Mws, biasws, W_out, b_out, out);
}

// Round 3
// 13989.926 us; speedup vs baseline: 2.3635x; 1.5723x over previous
//
#include <hip/hip_runtime.h>
#include <hip/hip_bf16.h>

#ifndef __has_builtin
#define __has_builtin(x) 0
#endif

#define LSEQ 32768
#define L2E 1.4426950408889634f

// DPP controls
#define DPP_XOR1 0xB1   // quad_perm [1,0,3,2]
#define DPP_XOR2 0x4E   // quad_perm [2,3,0,1]
#define DPP_XOR7 0x141  // row_half_mirror (lane ^ 7 within each 8)
#define DPPF(x, ctrl) __int_as_float(__builtin_amdgcn_update_dpp(0, __float_as_int(x), (ctrl), 0xF, 0xF, true))

typedef _Float16 h2v __attribute__((ext_vector_type(2)));

__device__ __forceinline__ float dot2(int m, int h, float acc) {
#if __has_builtin(__builtin_amdgcn_fdot2)
    return __builtin_amdgcn_fdot2(__builtin_bit_cast(h2v, m),
                                  __builtin_bit_cast(h2v, h), acc, false);
#else
    h2v mm = __builtin_bit_cast(h2v, m), hh = __builtin_bit_cast(h2v, h);
    return fmaf((float)mm[0], (float)hh[0], fmaf((float)mm[1], (float)hh[1], acc));
#endif
}

// ---------------- P1: xm[v][j] = b_im[j] + sum_e w_im[j,e]*emb[v,e] ----------------
__global__ void precompute_xm(const float* __restrict__ emb,
                              const float* __restrict__ w_im,
                              const float* __restrict__ b_im,
                              float* __restrict__ xmws) {
    int tid = (int)threadIdx.x;  // 384 threads: v = tid>>6, j = tid&63
    int v = tid >> 6, j = tid & 63;
    float acc = b_im[j];
    for (int e = 0; e < 32; ++e) acc = fmaf(w_im[j * 32 + e], emb[v * 32 + e], acc);
    xmws[v * 64 + j] = acc;
}

// ---------------- P2: M_v = s_r * W_hh . diag(xm_v) . W_hm  → packed f16 -----------
// Main-kernel lane tid = w*64 + jg*8 + gt*2 + hf  (ch=r&63, gt=r>>6, w=ch>>3, jg=ch&7)
// Lane's 32-half arm = cols [hf*32, hf*32+32) of row r, dword i holds cols (2i,2i+1).
// Stored at Mh[(((v*4+q)*512 + tid)*4 + c] with q=i>>2, c=i&3 (int4-coalesced).
__global__ void precompute_M(const float* __restrict__ emb,
                             const float* __restrict__ w_hm,
                             const float* __restrict__ b_hm,
                             const float* __restrict__ W_ih,
                             const float* __restrict__ b_ih,
                             const float* __restrict__ W_hh,
                             const float* __restrict__ b_hh,
                             const float* __restrict__ xmws,
                             unsigned int* __restrict__ Mh,
                             float* __restrict__ biasws) {
    int n = blockIdx.x * 256 + (int)threadIdx.x;  // 0..49151 = 6*256*32
    int v = n >> 13;
    int rem = n & 8191;
    int r = rem >> 5;
    int kp = rem & 31;        // half-pair index; k0 = 2*kp
    int k0 = kp * 2;
    int gt = r >> 6;
    float s = (gt == 2) ? (-2.0f * L2E) : (-L2E);
    float acc0 = 0.0f, acc1 = 0.0f;
    for (int jj = 0; jj < 64; ++jj) {
        float wx = W_hh[r * 64 + jj] * xmws[v * 64 + jj];
        acc0 = fmaf(wx, w_hm[jj * 64 + k0], acc0);
        acc1 = fmaf(wx, w_hm[jj * 64 + k0 + 1], acc1);
    }
    int ch = r & 63, w = ch >> 3, jg = ch & 7;
    int hf = k0 >> 5;
    int tid = w * 64 + jg * 8 + gt * 2 + hf;
    int i = kp & 15, q = i >> 2, c = i & 3;
    unsigned lo = (unsigned)__builtin_bit_cast(unsigned short, (_Float16)(s * acc0));
    unsigned hi = (unsigned)__builtin_bit_cast(unsigned short, (_Float16)(s * acc1));
    Mh[((v * 4 + q) * 512 + tid) * 4 + c] = lo | (hi << 16);
    if (kp == 0) {  // hf==0 lane: full bias (prescaled)
        float b = b_ih[r] + b_hh[r];
        for (int e = 0; e < 32; ++e) b = fmaf(W_ih[r * 32 + e], emb[v * 32 + e], b);
        for (int jj = 0; jj < 64; ++jj)
            b = fmaf(W_hh[r * 64 + jj] * xmws[v * 64 + jj], b_hm[jj], b);
        biasws[v * 512 + tid] = s * b;
    }
    if (kp == 16) biasws[v * 512 + tid] = 0.0f;  // hf==1 lane: zero
}

// ---------------- main serial kernel: 1 workgroup, 8 waves, channel-grouped -------
// Per step: 4 ds_read_b128 (h as f16) -> 16 v_dot2_f32_f16 -> DPP xor1 half-combine
// -> exp2/rcp activation -> 3 DPP gate butterfly + 8 cndmask -> c/h update ->
// 1 ds_write_b16 -> barrier. M arm for step t+2 streamed from L2 into named regs.
__global__ __launch_bounds__(512, 2) void mlstm_main(
    const int* __restrict__ seq,
    const int4* __restrict__ Mi4,
    const float* __restrict__ biasws,
    const float* __restrict__ W_out,
    const float* __restrict__ b_out,
    float* __restrict__ out)
{
    const int tid = (int)threadIdx.x;
    const int l = tid & 63;
    const int w = tid >> 6;
    const int hf = l & 1;
    const int p = (l >> 1) & 3;       // gate: 0=i 1=f 2=g 3=o
    const int ch = w * 8 + (l >> 3);  // this lane's channel
    const bool gb0 = (p & 1) != 0;
    const bool gb1 = (p & 2) != 0;
    const bool is_g = (p == 2);
    const float act_s = is_g ? 2.0f : 1.0f;
    const float act_b = is_g ? -1.0f : 0.0f;

    __shared__ __align__(16) unsigned short hbuf[2][64];
    __shared__ float cvec[64];

    if (tid < 64) hbuf[1][tid] = 0;

    // seq pipeline: pp0..pp7 = seq[t+2 .. t+9]
    int v0 = seq[0], v1 = seq[1];
    int pp0 = seq[2], pp1 = seq[3], pp2 = seq[4], pp3 = seq[5],
        pp4 = seq[6], pp5 = seq[7], pp6 = seq[8], pp7 = seq[9];

    // prime double buffer: A = arm(v0), B = arm(v1)
    int4 a0 = Mi4[(v0 * 4 + 0) * 512 + tid], a1 = Mi4[(v0 * 4 + 1) * 512 + tid],
         a2 = Mi4[(v0 * 4 + 2) * 512 + tid], a3 = Mi4[(v0 * 4 + 3) * 512 + tid];
    float ba = biasws[v0 * 512 + tid];
    int4 e0 = Mi4[(v1 * 4 + 0) * 512 + tid], e1 = Mi4[(v1 * 4 + 1) * 512 + tid],
         e2 = Mi4[(v1 * 4 + 2) * 512 + tid], e3 = Mi4[(v1 * 4 + 3) * 512 + tid];
    float be = biasws[v1 * 512 + tid];

    float cc = 0.0f;
    __syncthreads();

#define BODY(A0, A1, A2, A3, BA, VN, RB, WB) do {                                    \
    const int4* hb_ = (const int4*)(&hbuf[RB][hf << 5]);                             \
    int4 H0_ = hb_[0], H1_ = hb_[1], H2_ = hb_[2], H3_ = hb_[3];                     \
    float q0_ = BA, q1_ = 0.0f, q2_ = 0.0f, q3_ = 0.0f;                              \
    q0_ = dot2(A0.x, H0_.x, q0_); q1_ = dot2(A0.y, H0_.y, q1_);                      \
    q2_ = dot2(A0.z, H0_.z, q2_); q3_ = dot2(A0.w, H0_.w, q3_);                      \
    q0_ = dot2(A1.x, H1_.x, q0_); q1_ = dot2(A1.y, H1_.y, q1_);                      \
    q2_ = dot2(A1.z, H1_.z, q2_); q3_ = dot2(A1.w, H1_.w, q3_);                      \
    q0_ = dot2(A2.x, H2_.x, q0_); q1_ = dot2(A2.y, H2_.y, q1_);                      \
    q2_ = dot2(A2.z, H2_.z, q2_); q3_ = dot2(A2.w, H2_.w, q3_);                      \
    q0_ = dot2(A3.x, H3_.x, q0_); q1_ = dot2(A3.y, H3_.y, q1_);                      \
    q2_ = dot2(A3.z, H3_.z, q2_); q3_ = dot2(A3.w, H3_.w, q3_);                      \
    A0 = Mi4[((VN) * 4 + 0) * 512 + tid]; A1 = Mi4[((VN) * 4 + 1) * 512 + tid];      \
    A2 = Mi4[((VN) * 4 + 2) * 512 + tid]; A3 = Mi4[((VN) * 4 + 3) * 512 + tid];      \
    BA = biasws[(VN) * 512 + tid];                                                   \
    float acc_ = (q0_ + q1_) + (q2_ + q3_);                                          \
    float full_ = acc_ + DPPF(acc_, DPP_XOR1);                                       \
    float sg_ = __builtin_amdgcn_rcpf(1.0f + __builtin_amdgcn_exp2f(full_));         \
    float V_ = fmaf(act_s, sg_, act_b);                                              \
    float W_ = DPPF(V_, DPP_XOR2);                                                   \
    float X_ = DPPF(V_, DPP_XOR7);                                                   \
    float Y_ = DPPF(W_, DPP_XOR7);                                                   \
    float t0_ = gb0 ? W_ : V_, t1_ = gb0 ? X_ : Y_;                                  \
    float u0_ = gb0 ? V_ : W_, u1_ = gb0 ? Y_ : X_;                                  \
    float gi_ = gb1 ? t1_ : t0_, gf_ = gb1 ? u1_ : u0_;                              \
    float gg_ = gb1 ? t0_ : t1_, go_ = gb1 ? u0_ : u1_;                              \
    cc = fmaf(gf_, cc, gi_ * gg_);                                                   \
    float tc_ = fmaf(2.0f,                                                           \
        __builtin_amdgcn_rcpf(1.0f + __builtin_amdgcn_exp2f(cc * (-2.0f * L2E))),    \
        -1.0f);                                                                      \
    float hh_ = go_ * tc_;                                                           \
    if ((l & 7) == 0)                                                                \
        hbuf[WB][ch] = __builtin_bit_cast(unsigned short, (_Float16)hh_);            \
    __syncthreads();                                                                 \
} while (0)

    for (int t = 0; t < LSEQ; t += 2) {
        BODY(a0, a1, a2, a3, ba, pp0, 1, 0);   // step t   (even): reads hbuf[1], writes hbuf[0]
        BODY(e0, e1, e2, e3, be, pp1, 0, 1);   // step t+1 (odd)
        pp0 = pp2; pp1 = pp3; pp2 = pp4; pp3 = pp5; pp4 = pp6; pp5 = pp7;
        int i8 = t + 10; i8 = i8 < LSEQ ? i8 : LSEQ - 1;
        int i9 = t + 11; i9 = i9 < LSEQ ? i9 : LSEQ - 1;
        pp6 = seq[i8]; pp7 = seq[i9];
    }
#undef BODY

    if ((l & 7) == 0) cvec[ch] = cc;
    __syncthreads();
    if (tid < 8) {
        float sacc = b_out[tid];
        for (int k2 = 0; k2 < 64; ++k2)
            sacc = fmaf(W_out[tid * 64 + k2], cvec[k2], sacc);
        out[tid] = sacc;
    }
}

extern "C" void kernel_launch(void* const* d_in, const int* in_sizes, int n_in,
                              void* d_out, int out_size, void* d_ws, size_t ws_size,
                              hipStream_t stream) {
    const int*   seq   = (const int*)d_in[0];
    const float* emb   = (const float*)d_in[1];
    const float* w_im  = (const float*)d_in[2];
    const float* b_im  = (const float*)d_in[3];
    const float* w_hm  = (const float*)d_in[4];
    const float* b_hm  = (const float*)d_in[5];
    const float* W_ih  = (const float*)d_in[6];
    const float* b_ih  = (const float*)d_in[7];
    const float* W_hh  = (const float*)d_in[8];
    const float* b_hh  = (const float*)d_in[9];
    const float* W_out = (const float*)d_in[10];
    const float* b_out = (const float*)d_in[11];
    float* out = (float*)d_out;

    float* ws     = (float*)d_ws;
    float* xmws   = ws;                              // 384 floats
    float* biasws = ws + 384;                        // 3072 floats
    unsigned int* Mh = (unsigned int*)(ws + 3456);   // 49152 dwords (13824 B offset, 16B-aligned)

    precompute_xm<<<1, 384, 0, stream>>>(emb, w_im, b_im, xmws);
    precompute_M<<<192, 256, 0, stream>>>(emb, w_hm, b_hm, W_ih, b_ih,
                                          W_hh, b_hh, xmws, Mh, biasws);
    mlstm_main<<<1, 512, 0, stream>>>(seq, (const int4*)Mh, biasws, W_out, b_out, out);
}